// Round 2
// baseline (1225.408 us; speedup 1.0000x reference)
//
#include <hip/hip_runtime.h>
#include <hip/hip_bf16.h>

#define N_NODESC 100000
#define N_EDGESC 3200000
#define FDIM 512
#define MPAD 100096   // 782 * 128

typedef __attribute__((ext_vector_type(4))) float f32x4;
typedef __attribute__((ext_vector_type(8))) __bf16 bf16x8;
typedef unsigned long long u64;

__device__ __forceinline__ void gload_lds16(const void* g, void* l) {
  __builtin_amdgcn_global_load_lds(
      (const __attribute__((address_space(1))) unsigned int*)g,
      (__attribute__((address_space(3))) unsigned int*)l, 16, 0, 0);
}

// ---- x: f32 -> bf16, pad rows [N_NODES, MPAD) with zeros ----
__global__ void k_convert_x(const float* __restrict__ x, __bf16* __restrict__ xb) {
  long i = (long)blockIdx.x * blockDim.x + threadIdx.x;   // one per 8 elements
  long total = (long)MPAD * FDIM / 8;
  if (i >= total) return;
  long base = i * 8;
  long row = base >> 9;
  bf16x8 o;
  if (row < N_NODESC) {
    const float4* p = (const float4*)(x + base);
    float4 a = p[0], b = p[1];
    o[0] = (__bf16)a.x; o[1] = (__bf16)a.y; o[2] = (__bf16)a.z; o[3] = (__bf16)a.w;
    o[4] = (__bf16)b.x; o[5] = (__bf16)b.y; o[6] = (__bf16)b.z; o[7] = (__bf16)b.w;
  } else {
    #pragma unroll
    for (int t = 0; t < 8; ++t) o[t] = (__bf16)0.0f;
  }
  *(bf16x8*)(xb + base) = o;
}

// ---- weight: f32 [K][N] -> bf16 transposed wT [N][K] ----
__global__ void k_convert_wT(const float* __restrict__ w, __bf16* __restrict__ wT) {
  int i = blockIdx.x * 256 + threadIdx.x;
  if (i >= FDIM * FDIM) return;
  int k = i >> 9, n = i & (FDIM - 1);
  wT[n * FDIM + k] = (__bf16)w[i];
}

// ---- CSR build ----
__global__ void k_hist(const int* __restrict__ rows, int* __restrict__ row_off) {
  int e = blockIdx.x * 256 + threadIdx.x;
  if (e >= N_EDGESC) return;
  atomicAdd(&row_off[rows[e] + 1], 1);
}

// scan row_off (exclusive prefix of counts) AND write row_cur[i] = start of row i
__global__ void k_scan(int* __restrict__ row_off, int* __restrict__ row_cur) {
  __shared__ int part[1024];
  const int t = threadIdx.x;
  const int CH = (N_NODESC + 1023) / 1024;  // 98
  const int lo = t * CH;
  const int hi = min(lo + CH, N_NODESC);
  int s = 0;
  for (int i = lo; i < hi; ++i) s += row_off[1 + i];
  part[t] = s;
  __syncthreads();
  for (int d = 1; d < 1024; d <<= 1) {
    int v = part[t];
    int u = (t >= d) ? part[t - d] : 0;
    __syncthreads();
    part[t] = v + u;
    __syncthreads();
  }
  int run = (t == 0) ? 0 : part[t - 1];
  for (int i = lo; i < hi; ++i) {
    row_cur[i] = run;            // start offset of row i
    run += row_off[1 + i];
    row_off[1 + i] = run;
  }
  if (t == 0) row_off[0] = 0;
}

__global__ void k_scatter(const int* __restrict__ rows, const int* __restrict__ cols,
                          const float* __restrict__ vals, int* __restrict__ row_cur,
                          u64* __restrict__ edges) {
  int e = blockIdx.x * 256 + threadIdx.x;
  if (e >= N_EDGESC) return;
  const int r = rows[e];
  const int p = atomicAdd(&row_cur[r], 1);
  const u64 pk = ((u64)__float_as_uint(vals[e]) << 32) | (unsigned)cols[e];
  edges[p] = pk;
}

// ---- GEMM: support[MPAD][512] (bf16) = xb[MPAD][512] @ w[512][512] ----
// 128x128 tile, BK=32, 4 waves (2x2), 16x16x32 bf16 MFMA, global_load_lds x16
__global__ __launch_bounds__(256) void k_gemm(const __bf16* __restrict__ xb,
                                              const __bf16* __restrict__ wT,
                                              __bf16* __restrict__ support) {
  __shared__ __bf16 lA[2][128 * 32];
  __shared__ __bf16 lB[2][128 * 32];   // n-major: lB[n][k]
  const int tm = blockIdx.x >> 2;
  const int tn = blockIdx.x & 3;
  const int tid = threadIdx.x;
  const int wid = tid >> 6;
  const int lane = tid & 63;
  const int wm = wid >> 1;
  const int wn = wid & 1;

  const long rowA0 = (long)tm * 128;
  const int  ncol0 = tn * 128;

  const int srow  = lane >> 2;        // 0..15 within a 1KB chunk
  const int skoff = (lane & 3) * 8;   // bf16 elems

  f32x4 acc[4][4];
  #pragma unroll
  for (int m = 0; m < 4; ++m)
    #pragma unroll
    for (int n = 0; n < 4; ++n)
      acc[m][n] = (f32x4){0.f, 0.f, 0.f, 0.f};

  auto stage = [&](int buf, int kt) {
    const int k0 = kt * 32;
    #pragma unroll
    for (int it = 0; it < 2; ++it) {
      const int c = wid * 2 + it;               // chunk 0..7 (wave-uniform)
      const __bf16* gA = xb + (rowA0 + c * 16 + srow) * (long)FDIM + k0 + skoff;
      gload_lds16(gA, &lA[buf][c * 512]);
      const __bf16* gB = wT + (long)(ncol0 + c * 16 + srow) * FDIM + k0 + skoff;
      gload_lds16(gB, &lB[buf][c * 512]);
    }
  };

  stage(0, 0);
  __syncthreads();

  const int frow = lane & 15;
  const int fk   = (lane >> 4) * 8;

  for (int kt = 0; kt < 16; ++kt) {
    const int buf = kt & 1;
    if (kt + 1 < 16) stage(buf ^ 1, kt + 1);
    bf16x8 a[4], b[4];
    #pragma unroll
    for (int m = 0; m < 4; ++m)
      a[m] = *(const bf16x8*)&lA[buf][(wm * 64 + m * 16 + frow) * 32 + fk];
    #pragma unroll
    for (int n = 0; n < 4; ++n)
      b[n] = *(const bf16x8*)&lB[buf][(wn * 64 + n * 16 + frow) * 32 + fk];
    #pragma unroll
    for (int m = 0; m < 4; ++m)
      #pragma unroll
      for (int n = 0; n < 4; ++n)
        acc[m][n] = __builtin_amdgcn_mfma_f32_16x16x32_bf16(a[m], b[n], acc[m][n], 0, 0, 0);
    __syncthreads();
  }

  // C/D layout (m89-verified): col = lane&15, row = (lane>>4)*4 + i
  const long crow0 = (long)tm * 128 + wm * 64 + (lane >> 4) * 4;
  const int  ccol0 = tn * 128 + wn * 64 + frow;
  #pragma unroll
  for (int m = 0; m < 4; ++m)
    #pragma unroll
    for (int n = 0; n < 4; ++n)
      #pragma unroll
      for (int i = 0; i < 4; ++i)
        support[(crow0 + m * 16 + i) * (long)FDIM + ccol0 + n * 16] = (__bf16)acc[m][n][i];
}

// ---- SpMM: one wave per row, lane owns 8 features, 4-edge unroll + prefetch ----
__global__ __launch_bounds__(256) void k_spmm(const int* __restrict__ row_off,
                                              const u64* __restrict__ edges,
                                              const __bf16* __restrict__ support,
                                              float* __restrict__ out) {
  const int r = blockIdx.x * 4 + (threadIdx.x >> 6);
  const int lane = threadIdx.x & 63;
  if (r >= N_NODESC) return;
  const int beg = row_off[r];
  const int end = row_off[r + 1];
  const __bf16* sp = support + lane * 8;

  float acc[8];
  #pragma unroll
  for (int i = 0; i < 8; ++i) acc[i] = 0.f;

  int j = beg;
  if (j + 4 <= end) {
    u64 e0 = __builtin_nontemporal_load(edges + j);
    u64 e1 = __builtin_nontemporal_load(edges + j + 1);
    u64 e2 = __builtin_nontemporal_load(edges + j + 2);
    u64 e3 = __builtin_nontemporal_load(edges + j + 3);
    for (;;) {
      const int jn = j + 4;
      const bool more = (jn + 4 <= end);
      u64 f0 = 0, f1 = 0, f2 = 0, f3 = 0;
      if (more) {
        f0 = __builtin_nontemporal_load(edges + jn);
        f1 = __builtin_nontemporal_load(edges + jn + 1);
        f2 = __builtin_nontemporal_load(edges + jn + 2);
        f3 = __builtin_nontemporal_load(edges + jn + 3);
      }
      const bf16x8 s0 = *(const bf16x8*)(sp + (long)(unsigned)(e0 & 0xffffffffu) * FDIM);
      const bf16x8 s1 = *(const bf16x8*)(sp + (long)(unsigned)(e1 & 0xffffffffu) * FDIM);
      const bf16x8 s2 = *(const bf16x8*)(sp + (long)(unsigned)(e2 & 0xffffffffu) * FDIM);
      const bf16x8 s3 = *(const bf16x8*)(sp + (long)(unsigned)(e3 & 0xffffffffu) * FDIM);
      const float v0 = __uint_as_float((unsigned)(e0 >> 32));
      const float v1 = __uint_as_float((unsigned)(e1 >> 32));
      const float v2 = __uint_as_float((unsigned)(e2 >> 32));
      const float v3 = __uint_as_float((unsigned)(e3 >> 32));
      #pragma unroll
      for (int i = 0; i < 8; ++i) acc[i] += v0 * (float)s0[i];
      #pragma unroll
      for (int i = 0; i < 8; ++i) acc[i] += v1 * (float)s1[i];
      #pragma unroll
      for (int i = 0; i < 8; ++i) acc[i] += v2 * (float)s2[i];
      #pragma unroll
      for (int i = 0; i < 8; ++i) acc[i] += v3 * (float)s3[i];
      j = jn;
      if (!more) break;
      e0 = f0; e1 = f1; e2 = f2; e3 = f3;
    }
  }
  for (; j < end; ++j) {
    const u64 e = __builtin_nontemporal_load(edges + j);
    const bf16x8 s = *(const bf16x8*)(sp + (long)(unsigned)(e & 0xffffffffu) * FDIM);
    const float v = __uint_as_float((unsigned)(e >> 32));
    #pragma unroll
    for (int i = 0; i < 8; ++i) acc[i] += v * (float)s[i];
  }

  f32x4 o0 = {acc[0], acc[1], acc[2], acc[3]};
  f32x4 o1 = {acc[4], acc[5], acc[6], acc[7]};
  __builtin_nontemporal_store(o0, (f32x4*)(out + (long)r * FDIM + lane * 8));
  __builtin_nontemporal_store(o1, (f32x4*)(out + (long)r * FDIM + lane * 8 + 4));
}

extern "C" void kernel_launch(void* const* d_in, const int* in_sizes, int n_in,
                              void* d_out, int out_size, void* d_ws, size_t ws_size,
                              hipStream_t stream) {
  const float* x    = (const float*)d_in[0];
  const float* w    = (const float*)d_in[1];
  const int*   rows = (const int*)d_in[2];
  const int*   cols = (const int*)d_in[3];
  const float* vals = (const float*)d_in[4];
  float* out = (float*)d_out;

  char* ws = (char*)d_ws;
  size_t off = 0;
  auto alloc = [&](size_t bytes) {
    void* p = ws + off;
    off += (bytes + 255) & ~(size_t)255;
    return p;
  };
  __bf16* xb      = (__bf16*)alloc((size_t)MPAD * FDIM * 2);      // 102.5 MB
  __bf16* wT      = (__bf16*)alloc((size_t)FDIM * FDIM * 2);      // 0.5 MB
  __bf16* support = (__bf16*)alloc((size_t)MPAD * FDIM * 2);      // 102.5 MB
  int*    row_off = (int*)alloc((size_t)(N_NODESC + 1) * 4);
  int*    row_cur = (int*)alloc((size_t)(N_NODESC + 1) * 4);
  u64*    edges   = (u64*)alloc((size_t)N_EDGESC * 8);            // 25.6 MB
  (void)ws_size;

  hipMemsetAsync(row_off, 0, (size_t)(N_NODESC + 1) * 4, stream);

  k_convert_x<<<(int)(((long)MPAD * FDIM / 8 + 255) / 256), 256, 0, stream>>>(x, xb);
  k_convert_wT<<<(FDIM * FDIM + 255) / 256, 256, 0, stream>>>(w, wT);
  k_hist<<<(N_EDGESC + 255) / 256, 256, 0, stream>>>(rows, row_off);
  k_scan<<<1, 1024, 0, stream>>>(row_off, row_cur);
  k_scatter<<<(N_EDGESC + 255) / 256, 256, 0, stream>>>(rows, cols, vals, row_cur, edges);
  k_gemm<<<(MPAD / 128) * 4, 256, 0, stream>>>(xb, wT, support);
  k_spmm<<<N_NODESC / 4, 256, 0, stream>>>(row_off, edges, support, out);
}

// Round 3
// 984.748 us; speedup vs baseline: 1.2444x; 1.2444x over previous
//
#include <hip/hip_runtime.h>
#include <hip/hip_bf16.h>

#define N_NODESC 100000
#define N_EDGESC 3200000
#define FDIM 512
#define MPAD 100096   // 782 * 128
#define NBUCK 8       // col >> 14 -> 0..6 used
#define NOFF (N_NODESC * NBUCK)   // 800000 counts

typedef __attribute__((ext_vector_type(4))) float f32x4;
typedef __attribute__((ext_vector_type(8))) __bf16 bf16x8;
typedef unsigned long long u64;

__device__ __forceinline__ void gload_lds16(const void* g, void* l) {
  __builtin_amdgcn_global_load_lds(
      (const __attribute__((address_space(1))) unsigned int*)g,
      (__attribute__((address_space(3))) unsigned int*)l, 16, 0, 0);
}

// ---- x: f32 -> bf16, pad rows [N_NODES, MPAD) with zeros ----
__global__ void k_convert_x(const float* __restrict__ x, __bf16* __restrict__ xb) {
  long i = (long)blockIdx.x * blockDim.x + threadIdx.x;   // one per 8 elements
  long total = (long)MPAD * FDIM / 8;
  if (i >= total) return;
  long base = i * 8;
  long row = base >> 9;
  bf16x8 o;
  if (row < N_NODESC) {
    const float4* p = (const float4*)(x + base);
    float4 a = p[0], b = p[1];
    o[0] = (__bf16)a.x; o[1] = (__bf16)a.y; o[2] = (__bf16)a.z; o[3] = (__bf16)a.w;
    o[4] = (__bf16)b.x; o[5] = (__bf16)b.y; o[6] = (__bf16)b.z; o[7] = (__bf16)b.w;
  } else {
    #pragma unroll
    for (int t = 0; t < 8; ++t) o[t] = (__bf16)0.0f;
  }
  *(bf16x8*)(xb + base) = o;
}

// ---- weight: f32 [K][N] -> bf16 transposed wT [N][K] ----
__global__ void k_convert_wT(const float* __restrict__ w, __bf16* __restrict__ wT) {
  int i = blockIdx.x * 256 + threadIdx.x;
  if (i >= FDIM * FDIM) return;
  int k = i >> 9, n = i & (FDIM - 1);
  wT[n * FDIM + k] = (__bf16)w[i];
}

// ---- CSR build with column-bucket ordering inside each row ----
__global__ void k_hist(const int* __restrict__ rows, const int* __restrict__ cols,
                       int* __restrict__ off8) {
  int e = blockIdx.x * 256 + threadIdx.x;
  if (e >= N_EDGESC) return;
  const int r = rows[e];
  const int b = cols[e] >> 14;
  atomicAdd(&off8[r * NBUCK + b], 1);
}

// multi-block exclusive scan over off8[0..NOFF): 2048 elems/block
__global__ __launch_bounds__(1024) void k_scan1(int* __restrict__ d, int* __restrict__ bsum) {
  __shared__ int s[1024];
  const int t = threadIdx.x;
  const int base = blockIdx.x * 2048;
  const int i0 = base + 2 * t, i1 = i0 + 1;
  const int d0 = (i0 < NOFF) ? d[i0] : 0;
  const int d1 = (i1 < NOFF) ? d[i1] : 0;
  s[t] = d0 + d1;
  __syncthreads();
  for (int dl = 1; dl < 1024; dl <<= 1) {
    int v = s[t];
    int u = (t >= dl) ? s[t - dl] : 0;
    __syncthreads();
    s[t] = v + u;
    __syncthreads();
  }
  const int excl = (t == 0) ? 0 : s[t - 1];
  if (i0 < NOFF) d[i0] = excl;
  if (i1 < NOFF) d[i1] = excl + d0;
  if (t == 1023) bsum[blockIdx.x] = s[1023];
}

__global__ __launch_bounds__(1024) void k_scan2(int* __restrict__ bsum, int nb,
                                                int* __restrict__ d) {
  __shared__ int s[1024];
  const int t = threadIdx.x;
  s[t] = (t < nb) ? bsum[t] : 0;
  __syncthreads();
  for (int dl = 1; dl < 1024; dl <<= 1) {
    int v = s[t];
    int u = (t >= dl) ? s[t - dl] : 0;
    __syncthreads();
    s[t] = v + u;
    __syncthreads();
  }
  if (t < nb) bsum[t] = (t == 0) ? 0 : s[t - 1];
  if (t == 0) d[NOFF] = s[1023];   // total edge count
}

__global__ void k_scan3(int* __restrict__ d, const int* __restrict__ bsum,
                        int* __restrict__ cur) {
  int i = blockIdx.x * 256 + threadIdx.x;
  if (i >= NOFF) return;
  const int v = d[i] + bsum[i >> 11];
  d[i] = v;
  cur[i] = v;
}

__global__ void k_scatter(const int* __restrict__ rows, const int* __restrict__ cols,
                          const float* __restrict__ vals, int* __restrict__ cur,
                          u64* __restrict__ edges) {
  int e = blockIdx.x * 256 + threadIdx.x;
  if (e >= N_EDGESC) return;
  const int r = rows[e];
  const int c = cols[e];
  const int p = atomicAdd(&cur[r * NBUCK + (c >> 14)], 1);
  edges[p] = ((u64)__float_as_uint(vals[e]) << 32) | (unsigned)c;
}

// ---- GEMM: support[MPAD][512] (bf16) = xb[MPAD][512] @ w[512][512] ----
__global__ __launch_bounds__(256) void k_gemm(const __bf16* __restrict__ xb,
                                              const __bf16* __restrict__ wT,
                                              __bf16* __restrict__ support) {
  __shared__ __bf16 lA[2][128 * 32];
  __shared__ __bf16 lB[2][128 * 32];   // n-major: lB[n][k]
  const int tm = blockIdx.x >> 2;
  const int tn = blockIdx.x & 3;
  const int tid = threadIdx.x;
  const int wid = tid >> 6;
  const int lane = tid & 63;
  const int wm = wid >> 1;
  const int wn = wid & 1;

  const long rowA0 = (long)tm * 128;
  const int  ncol0 = tn * 128;

  const int srow  = lane >> 2;        // 0..15 within a 1KB chunk
  const int skoff = (lane & 3) * 8;   // bf16 elems

  f32x4 acc[4][4];
  #pragma unroll
  for (int m = 0; m < 4; ++m)
    #pragma unroll
    for (int n = 0; n < 4; ++n)
      acc[m][n] = (f32x4){0.f, 0.f, 0.f, 0.f};

  auto stage = [&](int buf, int kt) {
    const int k0 = kt * 32;
    #pragma unroll
    for (int it = 0; it < 2; ++it) {
      const int c = wid * 2 + it;               // chunk 0..7 (wave-uniform)
      const __bf16* gA = xb + (rowA0 + c * 16 + srow) * (long)FDIM + k0 + skoff;
      gload_lds16(gA, &lA[buf][c * 512]);
      const __bf16* gB = wT + (long)(ncol0 + c * 16 + srow) * FDIM + k0 + skoff;
      gload_lds16(gB, &lB[buf][c * 512]);
    }
  };

  stage(0, 0);
  __syncthreads();

  const int frow = lane & 15;
  const int fk   = (lane >> 4) * 8;

  for (int kt = 0; kt < 16; ++kt) {
    const int buf = kt & 1;
    if (kt + 1 < 16) stage(buf ^ 1, kt + 1);
    bf16x8 a[4], b[4];
    #pragma unroll
    for (int m = 0; m < 4; ++m)
      a[m] = *(const bf16x8*)&lA[buf][(wm * 64 + m * 16 + frow) * 32 + fk];
    #pragma unroll
    for (int n = 0; n < 4; ++n)
      b[n] = *(const bf16x8*)&lB[buf][(wn * 64 + n * 16 + frow) * 32 + fk];
    #pragma unroll
    for (int m = 0; m < 4; ++m)
      #pragma unroll
      for (int n = 0; n < 4; ++n)
        acc[m][n] = __builtin_amdgcn_mfma_f32_16x16x32_bf16(a[m], b[n], acc[m][n], 0, 0, 0);
    __syncthreads();
  }

  // C/D layout (m89-verified): col = lane&15, row = (lane>>4)*4 + i
  const long crow0 = (long)tm * 128 + wm * 64 + (lane >> 4) * 4;
  const int  ccol0 = tn * 128 + wn * 64 + frow;
  #pragma unroll
  for (int m = 0; m < 4; ++m)
    #pragma unroll
    for (int n = 0; n < 4; ++n)
      #pragma unroll
      for (int i = 0; i < 4; ++i)
        support[(crow0 + m * 16 + i) * (long)FDIM + ccol0 + n * 16] = (__bf16)acc[m][n][i];
}

// ---- SpMM: one wave per row, lane owns 8 features (R1 low-VGPR form) ----
__global__ __launch_bounds__(256) void k_spmm(const int* __restrict__ off8,
                                              const u64* __restrict__ edges,
                                              const __bf16* __restrict__ support,
                                              float* __restrict__ out) {
  const int r = blockIdx.x * 4 + (threadIdx.x >> 6);
  const int lane = threadIdx.x & 63;
  if (r >= N_NODESC) return;
  const int beg = off8[r * NBUCK];
  const int end = off8[r * NBUCK + NBUCK];   // start of next row (or total)
  const __bf16* sp = support + lane * 8;

  float acc[8];
  #pragma unroll
  for (int i = 0; i < 8; ++i) acc[i] = 0.f;

  int j = beg;
  for (; j + 1 < end; j += 2) {
    const u64 e0 = edges[j];
    const u64 e1 = edges[j + 1];
    const bf16x8 s0 = *(const bf16x8*)(sp + (long)(unsigned)(e0 & 0xffffffffu) * FDIM);
    const bf16x8 s1 = *(const bf16x8*)(sp + (long)(unsigned)(e1 & 0xffffffffu) * FDIM);
    const float v0 = __uint_as_float((unsigned)(e0 >> 32));
    const float v1 = __uint_as_float((unsigned)(e1 >> 32));
    #pragma unroll
    for (int i = 0; i < 8; ++i) acc[i] += v0 * (float)s0[i];
    #pragma unroll
    for (int i = 0; i < 8; ++i) acc[i] += v1 * (float)s1[i];
  }
  if (j < end) {
    const u64 e0 = edges[j];
    const bf16x8 s0 = *(const bf16x8*)(sp + (long)(unsigned)(e0 & 0xffffffffu) * FDIM);
    const float v0 = __uint_as_float((unsigned)(e0 >> 32));
    #pragma unroll
    for (int i = 0; i < 8; ++i) acc[i] += v0 * (float)s0[i];
  }

  *(float4*)(out + (long)r * FDIM + lane * 8) =
      make_float4(acc[0], acc[1], acc[2], acc[3]);
  *(float4*)(out + (long)r * FDIM + lane * 8 + 4) =
      make_float4(acc[4], acc[5], acc[6], acc[7]);
}

extern "C" void kernel_launch(void* const* d_in, const int* in_sizes, int n_in,
                              void* d_out, int out_size, void* d_ws, size_t ws_size,
                              hipStream_t stream) {
  const float* x    = (const float*)d_in[0];
  const float* w    = (const float*)d_in[1];
  const int*   rows = (const int*)d_in[2];
  const int*   cols = (const int*)d_in[3];
  const float* vals = (const float*)d_in[4];
  float* out = (float*)d_out;

  char* ws = (char*)d_ws;
  size_t off = 0;
  auto alloc = [&](size_t bytes) {
    void* p = ws + off;
    off += (bytes + 255) & ~(size_t)255;
    return p;
  };
  __bf16* xb      = (__bf16*)alloc((size_t)MPAD * FDIM * 2);      // 102.5 MB
  __bf16* wT      = (__bf16*)alloc((size_t)FDIM * FDIM * 2);      // 0.5 MB
  __bf16* support = (__bf16*)alloc((size_t)MPAD * FDIM * 2);      // 102.5 MB
  int*    off8    = (int*)alloc((size_t)(NOFF + 1) * 4);          // 3.2 MB
  int*    cur     = (int*)alloc((size_t)NOFF * 4);                // 3.2 MB
  int*    bsum    = (int*)alloc(1024 * 4);
  u64*    edges   = (u64*)alloc((size_t)N_EDGESC * 8);            // 25.6 MB
  (void)ws_size;

  const int NB_SCAN = (NOFF + 2047) / 2048;   // 391

  hipMemsetAsync(off8, 0, (size_t)(NOFF + 1) * 4, stream);

  k_convert_x<<<(int)(((long)MPAD * FDIM / 8 + 255) / 256), 256, 0, stream>>>(x, xb);
  k_convert_wT<<<(FDIM * FDIM + 255) / 256, 256, 0, stream>>>(w, wT);
  k_hist<<<(N_EDGESC + 255) / 256, 256, 0, stream>>>(rows, cols, off8);
  k_scan1<<<NB_SCAN, 1024, 0, stream>>>(off8, bsum);
  k_scan2<<<1, 1024, 0, stream>>>(bsum, NB_SCAN, off8);
  k_scan3<<<(NOFF + 255) / 256, 256, 0, stream>>>(off8, bsum, cur);
  k_scatter<<<(N_EDGESC + 255) / 256, 256, 0, stream>>>(rows, cols, vals, cur, edges);
  k_gemm<<<(MPAD / 128) * 4, 256, 0, stream>>>(xb, wT, support);
  k_spmm<<<N_NODESC / 4, 256, 0, stream>>>(off8, edges, support, out);
}